// Round 1
// baseline (1082.108 us; speedup 1.0000x reference)
//
#include <hip/hip_runtime.h>
#include <hip/hip_bf16.h>
#include <math.h>

#define N_TOK 16384
#define DIM   512
#define FDIM  2048
#define NEXP  8
#define TOPK  2
#define PAIRS (N_TOK*TOPK)             // 32768
#define PAIRS_PAD (PAIRS + NEXP*128)   // 33792
#define MAX_TILES (PAIRS_PAD/128)      // 264

typedef __hip_bfloat16 bf16;
typedef __attribute__((ext_vector_type(8))) short bf16x8;
typedef __attribute__((ext_vector_type(4))) float f32x4;
typedef __attribute__((ext_vector_type(8))) short s16x8;

__device__ __forceinline__ short f2bf(float f){
  union { float f; unsigned u; } v; v.f = f;
  unsigned r = v.u + 0x7fffu + ((v.u >> 16) & 1u);
  return (short)(r >> 16);
}

// ---------------- gating: fp32 logits, top-2, softmax ----------------
__global__ __launch_bounds__(256) void k_gate(const float* __restrict__ x,
    const float* __restrict__ gw, int* __restrict__ tidx, float* __restrict__ tw,
    int* __restrict__ counts){
  int lane = threadIdx.x & 63;
  int t = blockIdx.x*4 + (threadIdx.x >> 6);
  const float* xr = x + (size_t)t*DIM + lane*8;
  f32x4 x0 = *(const f32x4*)xr;
  f32x4 x1 = *(const f32x4*)(xr+4);
  float acc[NEXP];
  #pragma unroll
  for(int e=0;e<NEXP;e++) acc[e]=0.f;
  #pragma unroll
  for(int i=0;i<8;i++){
    float xv = (i<4)? x0[i] : x1[i-4];
    const float* wr = gw + (size_t)(lane*8+i)*NEXP;
    f32x4 w0 = *(const f32x4*)wr;
    f32x4 w1 = *(const f32x4*)(wr+4);
    acc[0]+=xv*w0[0]; acc[1]+=xv*w0[1]; acc[2]+=xv*w0[2]; acc[3]+=xv*w0[3];
    acc[4]+=xv*w1[0]; acc[5]+=xv*w1[1]; acc[6]+=xv*w1[2]; acc[7]+=xv*w1[3];
  }
  #pragma unroll
  for(int off=32; off; off>>=1){
    #pragma unroll
    for(int e=0;e<NEXP;e++) acc[e] += __shfl_xor(acc[e], off);
  }
  if(lane==0){
    int e0=0; float v0=acc[0];
    #pragma unroll
    for(int e=1;e<NEXP;e++) if(acc[e]>v0){v0=acc[e]; e0=e;}
    int e1=-1; float v1=-1e30f;
    #pragma unroll
    for(int e=0;e<NEXP;e++) if(e!=e0 && acc[e]>v1){v1=acc[e]; e1=e;}
    float z = expf(v1-v0);
    float w0 = 1.f/(1.f+z);
    tidx[t*2]=e0; tidx[t*2+1]=e1;
    tw[t*2]=w0; tw[t*2+1]=1.f-w0;
    atomicAdd(&counts[e0],1); atomicAdd(&counts[e1],1);
  }
}

// ---------------- routing tables ----------------
__global__ void k_route(const int* __restrict__ counts, int* __restrict__ offsets,
    int* __restrict__ ntiles, int* __restrict__ te, int* __restrict__ tb,
    int* __restrict__ token_list, float* __restrict__ coef){
  __shared__ int s_s[NEXP], s_e[NEXP];
  if(threadIdx.x==0){
    int off=0, nt=0;
    for(int e=0;e<NEXP;e++){
      offsets[e]=off;
      int c=counts[e];
      int tiles=(c+127)>>7;
      for(int i=0;i<tiles;i++){ te[nt]=e; tb[nt]=off+(i<<7); nt++; }
      s_s[e]=off+c; s_e[e]=off+(tiles<<7);
      off += tiles<<7;
    }
    *ntiles=nt;
  }
  __syncthreads();
  for(int e=0;e<NEXP;e++)
    for(int i=s_s[e]+threadIdx.x; i<s_e[e]; i+=64){ token_list[i]=-1; coef[i]=0.f; }
}

__global__ __launch_bounds__(256) void k_scatter(const int* __restrict__ tidx,
    const float* __restrict__ tw, const int* __restrict__ offsets,
    int* __restrict__ fill, int* __restrict__ token_list, float* __restrict__ coef){
  int i = blockIdx.x*256 + threadIdx.x;
  if(i >= PAIRS) return;
  int e = tidx[i];
  int p = atomicAdd(&fill[e],1);
  int pos = offsets[e]+p;
  token_list[pos] = i>>1;
  coef[pos] = tw[i];
}

// ---------------- fp32 -> bf16 cast (x) ----------------
__global__ __launch_bounds__(256) void k_cast(const float* __restrict__ x,
                                              bf16* __restrict__ xb){
  int i = blockIdx.x*256 + threadIdx.x;   // handles 8 elements
  const float* p = x + (size_t)i*8;
  f32x4 a = *(const f32x4*)p;
  f32x4 b = *(const f32x4*)(p+4);
  s16x8 r;
  r[0]=f2bf(a[0]); r[1]=f2bf(a[1]); r[2]=f2bf(a[2]); r[3]=f2bf(a[3]);
  r[4]=f2bf(b[0]); r[5]=f2bf(b[1]); r[6]=f2bf(b[2]); r[7]=f2bf(b[3]);
  *(s16x8*)((short*)xb + (size_t)i*8) = r;
}

// ---------------- transpose+cast: src [R][C] f32 -> dst [C][R] bf16 (per expert z) ----------------
__global__ __launch_bounds__(256) void k_transpose(const float* __restrict__ src,
    bf16* __restrict__ dst, int R, int C){
  __shared__ float tile[32][33];
  const float* s = src + (size_t)blockIdx.z*R*C;
  short* d = (short*)dst + (size_t)blockIdx.z*R*C;
  int c0 = blockIdx.x*32, r0 = blockIdx.y*32;
  int tx = threadIdx.x & 31, ty = threadIdx.x >> 5;   // 32x8
  #pragma unroll
  for(int i=0;i<4;i++) tile[ty+8*i][tx] = s[(size_t)(r0+ty+8*i)*C + c0+tx];
  __syncthreads();
  #pragma unroll
  for(int i=0;i<4;i++) d[(size_t)(c0+ty+8*i)*R + r0+tx] = f2bf(tile[tx][ty+8*i]);
}

// ---------------- GEMM A: H = silu(X@w1) * (X@w3), gathered rows ----------------
__global__ __launch_bounds__(256,2) void k_gemmA(const bf16* __restrict__ xb,
    const bf16* __restrict__ w1T, const bf16* __restrict__ w3T,
    const int* __restrict__ ntiles, const int* __restrict__ te, const int* __restrict__ tb,
    const int* __restrict__ token_list, bf16* __restrict__ H){
  int tile = blockIdx.x;
  if(tile >= *ntiles) return;
  int e = te[tile], base = tb[tile];
  int f0 = blockIdx.y*128;
  __shared__ short As[128][40];
  __shared__ short B1s[128][40];
  __shared__ short B3s[128][40];
  int tid = threadIdx.x;
  int row = tid>>1, half = tid&1;
  int tok = token_list[base+row]; if(tok<0) tok=0;
  const short* pA  = (const short*)xb + (size_t)tok*DIM + half*16;
  const short* pB1 = (const short*)w1T + ((size_t)e*FDIM + f0 + row)*DIM + half*16;
  const short* pB3 = (const short*)w3T + ((size_t)e*FDIM + f0 + row)*DIM + half*16;
  int wid = tid>>6, lane = tid&63;
  int wr = wid>>1, wc = wid&1;
  int lrow = lane&15, lk = (lane>>4)<<3;
  f32x4 acc1[4][4] = {};
  f32x4 acc3[4][4] = {};
  for(int d0=0; d0<DIM; d0+=32){
    int4 a0  = *(const int4*)(pA  + d0);
    int4 a1  = *(const int4*)(pA  + d0 + 8);
    int4 b10 = *(const int4*)(pB1 + d0);
    int4 b11 = *(const int4*)(pB1 + d0 + 8);
    int4 b30 = *(const int4*)(pB3 + d0);
    int4 b31 = *(const int4*)(pB3 + d0 + 8);
    __syncthreads();
    *(int4*)&As[row][half*16]  = a0;  *(int4*)&As[row][half*16+8]  = a1;
    *(int4*)&B1s[row][half*16] = b10; *(int4*)&B1s[row][half*16+8] = b11;
    *(int4*)&B3s[row][half*16] = b30; *(int4*)&B3s[row][half*16+8] = b31;
    __syncthreads();
    bf16x8 af[4], bf1[4], bf3[4];
    #pragma unroll
    for(int m=0;m<4;m++) af[m] = *(const bf16x8*)&As[wr*64+m*16+lrow][lk];
    #pragma unroll
    for(int n=0;n<4;n++){ bf1[n] = *(const bf16x8*)&B1s[wc*64+n*16+lrow][lk];
                          bf3[n] = *(const bf16x8*)&B3s[wc*64+n*16+lrow][lk]; }
    #pragma unroll
    for(int m=0;m<4;m++){
      #pragma unroll
      for(int n=0;n<4;n++){
        acc1[m][n] = __builtin_amdgcn_mfma_f32_16x16x32_bf16(af[m], bf1[n], acc1[m][n], 0,0,0);
        acc3[m][n] = __builtin_amdgcn_mfma_f32_16x16x32_bf16(af[m], bf3[n], acc3[m][n], 0,0,0);
      }
    }
  }
  #pragma unroll
  for(int m=0;m<4;m++){
    int r0 = base + wr*64 + m*16 + ((lane>>4)<<2);
    #pragma unroll
    for(int n=0;n<4;n++){
      int col = f0 + wc*64 + n*16 + lrow;
      #pragma unroll
      for(int j=0;j<4;j++){
        float a = acc1[m][n][j];
        float h = a * (1.f/(1.f+__expf(-a))) * acc3[m][n][j];
        ((short*)H)[(size_t)(r0+j)*FDIM + col] = f2bf(h);
      }
    }
  }
}

// ---------------- GEMM B: out[tok] += coef * (H @ w2) ----------------
__global__ __launch_bounds__(256,2) void k_gemmB(const bf16* __restrict__ H,
    const bf16* __restrict__ w2T, const int* __restrict__ ntiles,
    const int* __restrict__ te, const int* __restrict__ tb,
    const int* __restrict__ token_list, const float* __restrict__ coef,
    float* __restrict__ out){
  int tile = blockIdx.x;
  if(tile >= *ntiles) return;
  int e = te[tile], base = tb[tile];
  int n0 = blockIdx.y*128;
  __shared__ short As[128][40];
  __shared__ short Bs[128][40];
  int tid = threadIdx.x, row = tid>>1, half = tid&1;
  const short* pA = (const short*)H + (size_t)(base+row)*FDIM + half*16;
  const short* pB = (const short*)w2T + ((size_t)e*DIM + n0 + row)*FDIM + half*16;
  int wid = tid>>6, lane = tid&63, wr = wid>>1, wc = wid&1;
  int lrow = lane&15, lk = (lane>>4)<<3;
  f32x4 acc[4][4] = {};
  for(int k0=0; k0<FDIM; k0+=32){
    int4 a0 = *(const int4*)(pA+k0), a1 = *(const int4*)(pA+k0+8);
    int4 b0 = *(const int4*)(pB+k0), b1 = *(const int4*)(pB+k0+8);
    __syncthreads();
    *(int4*)&As[row][half*16] = a0; *(int4*)&As[row][half*16+8] = a1;
    *(int4*)&Bs[row][half*16] = b0; *(int4*)&Bs[row][half*16+8] = b1;
    __syncthreads();
    bf16x8 af[4], bfr[4];
    #pragma unroll
    for(int m=0;m<4;m++) af[m]  = *(const bf16x8*)&As[wr*64+m*16+lrow][lk];
    #pragma unroll
    for(int n=0;n<4;n++) bfr[n] = *(const bf16x8*)&Bs[wc*64+n*16+lrow][lk];
    #pragma unroll
    for(int m=0;m<4;m++){
      #pragma unroll
      for(int n=0;n<4;n++)
        acc[m][n] = __builtin_amdgcn_mfma_f32_16x16x32_bf16(af[m], bfr[n], acc[m][n], 0,0,0);
    }
  }
  #pragma unroll
  for(int m=0;m<4;m++){
    #pragma unroll
    for(int j=0;j<4;j++){
      int r = base + wr*64 + m*16 + ((lane>>4)<<2) + j;
      int tok = token_list[r];
      if(tok<0) continue;
      float c = coef[r];
      #pragma unroll
      for(int n=0;n<4;n++){
        int col = n0 + wc*64 + n*16 + lrow;
        atomicAdd(out + (size_t)tok*DIM + col, c*acc[m][n][j]);
      }
    }
  }
}

extern "C" void kernel_launch(void* const* d_in, const int* in_sizes, int n_in,
                              void* d_out, int out_size, void* d_ws, size_t ws_size,
                              hipStream_t stream){
  const float* x  = (const float*)d_in[0];
  const float* gw = (const float*)d_in[1];
  const float* w1 = (const float*)d_in[2];
  const float* w2 = (const float*)d_in[3];
  const float* w3 = (const float*)d_in[4];
  float* out = (float*)d_out;
  char* ws = (char*)d_ws;

  // ws layout
  int* cw = (int*)ws;
  int* counts = cw;          // 8
  int* fill   = cw + 8;      // 8
  int* offsets= cw + 16;     // 8
  int* ntiles = cw + 24;     // 1
  int* te = cw + 32;         // 264
  int* tb = cw + 296;        // 264
  int* token_list = cw + 560;                         // PAIRS_PAD
  float* coef = (float*)(cw + 560 + PAIRS_PAD);       // PAIRS_PAD
  int* tidx   = cw + 560 + 2*PAIRS_PAD;               // PAIRS
  float* tw   = (float*)(cw + 560 + 2*PAIRS_PAD + PAIRS); // PAIRS
  const size_t MB16 = 16777216u;
  bf16* xb  = (bf16*)(ws + (1u<<20));
  bf16* w1T = (bf16*)(ws + (1u<<20) + 1u*MB16);
  bf16* w3T = (bf16*)(ws + (1u<<20) + 2u*MB16);
  bf16* w2T = (bf16*)(ws + (1u<<20) + 3u*MB16);
  bf16* Hbuf= (bf16*)(ws + (1u<<20) + 4u*MB16);
  size_t needed = (1u<<20) + 4u*MB16 + (size_t)PAIRS_PAD*FDIM*2u;
  if(ws_size < needed) return;  // ws too small: fail visibly (poisoned out)

  hipMemsetAsync(d_ws, 0, 256, stream);
  hipMemsetAsync(d_out, 0, (size_t)N_TOK*DIM*sizeof(float), stream);

  k_gate<<<N_TOK/4, 256, 0, stream>>>(x, gw, tidx, tw, counts);
  k_route<<<1, 64, 0, stream>>>(counts, offsets, ntiles, te, tb, token_list, coef);
  k_scatter<<<PAIRS/256, 256, 0, stream>>>(tidx, tw, offsets, fill, token_list, coef);
  k_cast<<<(N_TOK*DIM/8)/256, 256, 0, stream>>>(x, xb);
  k_transpose<<<dim3(FDIM/32, DIM/32, NEXP), 256, 0, stream>>>(w1, w1T, DIM, FDIM);
  k_transpose<<<dim3(FDIM/32, DIM/32, NEXP), 256, 0, stream>>>(w3, w3T, DIM, FDIM);
  k_transpose<<<dim3(DIM/32, FDIM/32, NEXP), 256, 0, stream>>>(w2, w2T, FDIM, DIM);
  k_gemmA<<<dim3(MAX_TILES, FDIM/128), 256, 0, stream>>>(xb, w1T, w3T, ntiles, te, tb, token_list, Hbuf);
  k_gemmB<<<dim3(MAX_TILES, DIM/128), 256, 0, stream>>>(Hbuf, w2T, ntiles, te, tb, token_list, coef, out);
}

// Round 5
// 514.367 us; speedup vs baseline: 2.1038x; 2.1038x over previous
//
#include <hip/hip_runtime.h>
#include <hip/hip_bf16.h>
#include <math.h>

#define N_TOK 16384
#define DIM   512
#define FDIM  2048
#define NEXP  8
#define TOPK  2
#define PAIRS (N_TOK*TOPK)             // 32768
#define MAX_TILES (PAIRS/128 + NEXP)   // 264

typedef __hip_bfloat16 bf16;
typedef __attribute__((ext_vector_type(8))) short bf16x8;
typedef __attribute__((ext_vector_type(4))) float f32x4;
typedef __attribute__((ext_vector_type(8))) short s16x8;

__device__ __forceinline__ short f2bf(float f){
  union { float f; unsigned u; } v; v.f = f;
  unsigned r = v.u + 0x7fffu + ((v.u >> 16) & 1u);
  return (short)(r >> 16);
}
__device__ __forceinline__ float bf2f(short s){
  union { unsigned u; float f; } v; v.u = ((unsigned)(unsigned short)s) << 16;
  return v.f;
}
// async global->LDS, 16B per lane. LDS dest = wave-uniform base + lane*16.
__device__ __forceinline__ void g2l16(const void* g, void* l){
  __builtin_amdgcn_global_load_lds(
      (const __attribute__((address_space(1))) unsigned int*)g,
      (__attribute__((address_space(3))) unsigned int*)l, 16, 0, 0);
}

// ---------------- gating: fp32 logits, top-2, softmax. NO global atomics ----------------
__global__ __launch_bounds__(512) void k_gate(const float* __restrict__ x,
    const float* __restrict__ gw, int* __restrict__ tidx, float* __restrict__ tw){
  __shared__ float gwT[NEXP][DIM];     // 16 KB, transposed: gwT[e][d]
  int tid = threadIdx.x;
  #pragma unroll
  for(int i=0;i<8;i++){
    int idx = tid + 512*i;             // 4096 floats
    gwT[idx&7][idx>>3] = gw[idx];
  }
  __syncthreads();
  int lane = tid & 63, wid = tid >> 6;
  int t = blockIdx.x*8 + wid;
  const float* xr = x + (size_t)t*DIM;
  float acc[NEXP];
  #pragma unroll
  for(int e=0;e<NEXP;e++) acc[e]=0.f;
  #pragma unroll
  for(int c=0;c<8;c++){
    float xv = xr[c*64 + lane];        // coalesced 256B per wave-load
    #pragma unroll
    for(int e=0;e<NEXP;e++) acc[e] += xv * gwT[e][c*64+lane];  // stride-1: conflict-free
  }
  #pragma unroll
  for(int off=32; off; off>>=1){
    #pragma unroll
    for(int e=0;e<NEXP;e++) acc[e] += __shfl_xor(acc[e], off);
  }
  if(lane==0){
    int e0=0; float v0=acc[0];
    #pragma unroll
    for(int e=1;e<NEXP;e++) if(acc[e]>v0){v0=acc[e]; e0=e;}
    int e1=-1; float v1=-1e30f;
    #pragma unroll
    for(int e=0;e<NEXP;e++) if(e!=e0 && acc[e]>v1){v1=acc[e]; e1=e;}
    float z = expf(v1-v0);
    float w0 = 1.f/(1.f+z);
    tidx[t*2]=e0; tidx[t*2+1]=e1;
    tw[t*2]=w0; tw[t*2+1]=1.f-w0;
  }
}

// ---------------- histogram: 8 global atomics per block ----------------
__global__ __launch_bounds__(256) void k_count(const int* __restrict__ tidx,
                                               int* __restrict__ counts){
  __shared__ int h[NEXP];
  if(threadIdx.x<NEXP) h[threadIdx.x]=0;
  __syncthreads();
  int i0 = blockIdx.x*1024 + threadIdx.x;
  #pragma unroll
  for(int k=0;k<4;k++) atomicAdd(&h[tidx[i0 + 256*k]], 1);
  __syncthreads();
  if(threadIdx.x<NEXP) atomicAdd(&counts[threadIdx.x], h[threadIdx.x]);
}

// ---------------- routing tables: dense offsets, ragged tiles ----------------
__global__ void k_route(const int* __restrict__ counts, int* __restrict__ offsets,
    int* __restrict__ ntiles, int* __restrict__ te, int* __restrict__ tb,
    int* __restrict__ ts){
  if(threadIdx.x==0){
    int off=0, nt=0;
    for(int e=0;e<NEXP;e++){
      offsets[e]=off;
      int c=counts[e];
      int tiles=(c+127)>>7;
      for(int i=0;i<tiles;i++){ te[nt]=e; tb[nt]=off+(i<<7); ts[nt]=off+c; nt++; }
      off += c;
    }
    *ntiles=nt;
  }
}

// ---------------- scatter: block-level reservation, dense positions ----------------
__global__ __launch_bounds__(256) void k_scatter(const int* __restrict__ tidx,
    const int* __restrict__ offsets, int* __restrict__ fill,
    int* __restrict__ token_list, int* __restrict__ posmap){
  __shared__ int lcnt[NEXP], lbase[NEXP];
  if(threadIdx.x<NEXP) lcnt[threadIdx.x]=0;
  __syncthreads();
  int i = blockIdx.x*256 + threadIdx.x;
  int e = tidx[i];
  int rank = atomicAdd(&lcnt[e], 1);          // LDS atomic: cheap
  __syncthreads();
  if(threadIdx.x<NEXP) lbase[threadIdx.x] = atomicAdd(&fill[threadIdx.x], lcnt[threadIdx.x]);
  __syncthreads();
  int pos = offsets[e] + lbase[e] + rank;
  token_list[pos] = i>>1;
  posmap[i] = pos;
}

// ---------------- fp32 -> bf16 cast (x) ----------------
__global__ __launch_bounds__(256) void k_cast(const float* __restrict__ x,
                                              bf16* __restrict__ xb){
  int i = blockIdx.x*256 + threadIdx.x;
  const float* p = x + (size_t)i*8;
  f32x4 a = *(const f32x4*)p;
  f32x4 b = *(const f32x4*)(p+4);
  s16x8 r;
  r[0]=f2bf(a[0]); r[1]=f2bf(a[1]); r[2]=f2bf(a[2]); r[3]=f2bf(a[3]);
  r[4]=f2bf(b[0]); r[5]=f2bf(b[1]); r[6]=f2bf(b[2]); r[7]=f2bf(b[3]);
  *(s16x8*)((short*)xb + (size_t)i*8) = r;
}

// ---------------- transpose+cast: src [R][C] f32 -> dst [C][R] bf16 ----------------
__global__ __launch_bounds__(256) void k_transpose(const float* __restrict__ src,
    bf16* __restrict__ dst, int R, int C){
  __shared__ float tile[32][33];
  const float* s = src + (size_t)blockIdx.z*R*C;
  short* d = (short*)dst + (size_t)blockIdx.z*R*C;
  int c0 = blockIdx.x*32, r0 = blockIdx.y*32;
  int tx = threadIdx.x & 31, ty = threadIdx.x >> 5;
  #pragma unroll
  for(int i=0;i<4;i++) tile[ty+8*i][tx] = s[(size_t)(r0+ty+8*i)*C + c0+tx];
  __syncthreads();
  #pragma unroll
  for(int i=0;i<4;i++) d[(size_t)(c0+ty+8*i)*R + r0+tx] = f2bf(tile[tx][ty+8*i]);
}

// ---------------- GEMM A: H[pos] = silu(X@w1) * (X@w3), gathered rows ----------------
// global_load_lds staging (m97 structure): linear LDS [128][32], 2 barriers/K-step.
__global__ __launch_bounds__(256,2) void k_gemmA(const bf16* __restrict__ xb,
    const bf16* __restrict__ w1T, const bf16* __restrict__ w3T,
    const int* __restrict__ ntiles, const int* __restrict__ te,
    const int* __restrict__ tb, const int* __restrict__ ts,
    const int* __restrict__ token_list, bf16* __restrict__ H){
  int tile = blockIdx.x;
  if(tile >= *ntiles) return;
  int e = te[tile], base = tb[tile], send = ts[tile];
  int f0 = blockIdx.y*128;
  __shared__ short As[128*32];
  __shared__ short B1s[128*32];
  __shared__ short B3s[128*32];
  int tid = threadIdx.x;
  // staging: instr i covers flat elems i*2048 + tid*8 -> row=i*64+(tid>>2), col=(tid&3)*8
  int srow0 = tid>>2, srow1 = 64 + (tid>>2), scol = (tid&3)*8;
  int r0g = base + srow0, r1g = base + srow1;
  int tok0 = token_list[(r0g < send) ? r0g : base];
  int tok1 = token_list[(r1g < send) ? r1g : base];
  const short* gA0  = (const short*)xb + (size_t)tok0*DIM + scol;
  const short* gA1  = (const short*)xb + (size_t)tok1*DIM + scol;
  const short* gB10 = (const short*)w1T + ((size_t)e*FDIM + f0 + srow0)*DIM + scol;
  const short* gB11 = (const short*)w1T + ((size_t)e*FDIM + f0 + srow1)*DIM + scol;
  const short* gB30 = (const short*)w3T + ((size_t)e*FDIM + f0 + srow0)*DIM + scol;
  const short* gB31 = (const short*)w3T + ((size_t)e*FDIM + f0 + srow1)*DIM + scol;
  char* lA  = (char*)As  + tid*16;
  char* lB1 = (char*)B1s + tid*16;
  char* lB3 = (char*)B3s + tid*16;
  int wid = tid>>6, lane = tid&63;
  int wr = wid>>1, wc = wid&1;
  int lrow = lane&15, lk = (lane>>4)<<3;
  f32x4 acc1[4][4] = {};
  f32x4 acc3[4][4] = {};
  for(int d0=0; d0<DIM; d0+=32){
    __syncthreads();                       // prev-iter fragment reads complete
    g2l16(gA0  + d0, lA);
    g2l16(gA1  + d0, lA  + 4096);
    g2l16(gB10 + d0, lB1);
    g2l16(gB11 + d0, lB1 + 4096);
    g2l16(gB30 + d0, lB3);
    g2l16(gB31 + d0, lB3 + 4096);
    __syncthreads();                       // vmcnt(0) drained before barrier
    bf16x8 af[4], bf1[4], bf3[4];
    #pragma unroll
    for(int m=0;m<4;m++) af[m] = *(const bf16x8*)&As[(wr*64+m*16+lrow)*32 + lk];
    #pragma unroll
    for(int n=0;n<4;n++){ bf1[n] = *(const bf16x8*)&B1s[(wc*64+n*16+lrow)*32 + lk];
                          bf3[n] = *(const bf16x8*)&B3s[(wc*64+n*16+lrow)*32 + lk]; }
    #pragma unroll
    for(int m=0;m<4;m++){
      #pragma unroll
      for(int n=0;n<4;n++){
        acc1[m][n] = __builtin_amdgcn_mfma_f32_16x16x32_bf16(af[m], bf1[n], acc1[m][n], 0,0,0);
        acc3[m][n] = __builtin_amdgcn_mfma_f32_16x16x32_bf16(af[m], bf3[n], acc3[m][n], 0,0,0);
      }
    }
  }
  #pragma unroll
  for(int m=0;m<4;m++){
    int r0 = base + wr*64 + m*16 + ((lane>>4)<<2);
    #pragma unroll
    for(int n=0;n<4;n++){
      int col = f0 + wc*64 + n*16 + lrow;
      #pragma unroll
      for(int j=0;j<4;j++){
        if(r0+j < send){
          float a = acc1[m][n][j];
          float h = a * (1.f/(1.f+__expf(-a))) * acc3[m][n][j];
          ((short*)H)[(size_t)(r0+j)*FDIM + col] = f2bf(h);
        }
      }
    }
  }
}

// ---------------- GEMM B: O[pos] = H[pos] @ w2  (no atomics) ----------------
__global__ __launch_bounds__(256,2) void k_gemmB(const bf16* __restrict__ H,
    const bf16* __restrict__ w2T, const int* __restrict__ ntiles,
    const int* __restrict__ te, const int* __restrict__ tb,
    const int* __restrict__ ts, bf16* __restrict__ O){
  int tile = blockIdx.x;
  if(tile >= *ntiles) return;
  int e = te[tile], base = tb[tile], send = ts[tile];
  int n0 = blockIdx.y*128;
  __shared__ short As[128*32];
  __shared__ short Bs[128*32];
  int tid = threadIdx.x;
  int srow0 = tid>>2, srow1 = 64 + (tid>>2), scol = (tid&3)*8;
  int r0g = base + srow0, r1g = base + srow1;
  int ar0 = (r0g < send) ? r0g : base;
  int ar1 = (r1g < send) ? r1g : base;
  const short* gA0 = (const short*)H + (size_t)ar0*FDIM + scol;
  const short* gA1 = (const short*)H + (size_t)ar1*FDIM + scol;
  const short* gB0 = (const short*)w2T + ((size_t)e*DIM + n0 + srow0)*FDIM + scol;
  const short* gB1 = (const short*)w2T + ((size_t)e*DIM + n0 + srow1)*FDIM + scol;
  char* lA = (char*)As + tid*16;
  char* lB = (char*)Bs + tid*16;
  int wid = tid>>6, lane = tid&63, wr = wid>>1, wc = wid&1;
  int lrow = lane&15, lk = (lane>>4)<<3;
  f32x4 acc[4][4] = {};
  for(int k0=0; k0<FDIM; k0+=32){
    __syncthreads();
    g2l16(gA0 + k0, lA);
    g2l16(gA1 + k0, lA + 4096);
    g2l16(gB0 + k0, lB);
    g2l16(gB1 + k0, lB + 4096);
    __syncthreads();
    bf16x8 af[4], bfr[4];
    #pragma unroll
    for(int m=0;m<4;m++) af[m]  = *(const bf16x8*)&As[(wr*64+m*16+lrow)*32 + lk];
    #pragma unroll
    for(int n=0;n<4;n++) bfr[n] = *(const bf16x8*)&Bs[(wc*64+n*16+lrow)*32 + lk];
    #pragma unroll
    for(int m=0;m<4;m++){
      #pragma unroll
      for(int n=0;n<4;n++)
        acc[m][n] = __builtin_amdgcn_mfma_f32_16x16x32_bf16(af[m], bfr[n], acc[m][n], 0,0,0);
    }
  }
  #pragma unroll
  for(int m=0;m<4;m++){
    #pragma unroll
    for(int j=0;j<4;j++){
      int r2 = base + wr*64 + m*16 + ((lane>>4)<<2) + j;
      if(r2 < send){
        #pragma unroll
        for(int n=0;n<4;n++){
          int col = n0 + wc*64 + n*16 + lrow;
          ((short*)O)[(size_t)r2*DIM + col] = f2bf(acc[m][n][j]);
        }
      }
    }
  }
}

// ---------------- combine: out[t] = w0*O[p0] + w1*O[p1] ----------------
__global__ __launch_bounds__(256) void k_combine(const bf16* __restrict__ O,
    const int* __restrict__ posmap, const float* __restrict__ tw,
    float* __restrict__ out){
  int lane = threadIdx.x & 63, wid = threadIdx.x >> 6;
  int t = blockIdx.x*4 + wid;
  int p0 = posmap[2*t], p1 = posmap[2*t+1];
  float w0 = tw[2*t], w1 = tw[2*t+1];
  s16x8 a = *(const s16x8*)((const short*)O + (size_t)p0*DIM + lane*8);
  s16x8 b = *(const s16x8*)((const short*)O + (size_t)p1*DIM + lane*8);
  f32x4 r0, r1;
  #pragma unroll
  for(int j=0;j<4;j++) r0[j] = w0*bf2f(a[j]) + w1*bf2f(b[j]);
  #pragma unroll
  for(int j=0;j<4;j++) r1[j] = w0*bf2f(a[4+j]) + w1*bf2f(b[4+j]);
  float* o = out + (size_t)t*DIM + lane*8;
  *(f32x4*)o = r0;
  *(f32x4*)(o+4) = r1;
}

extern "C" void kernel_launch(void* const* d_in, const int* in_sizes, int n_in,
                              void* d_out, int out_size, void* d_ws, size_t ws_size,
                              hipStream_t stream){
  const float* x  = (const float*)d_in[0];
  const float* gw = (const float*)d_in[1];
  const float* w1 = (const float*)d_in[2];
  const float* w2 = (const float*)d_in[3];
  const float* w3 = (const float*)d_in[4];
  float* out = (float*)d_out;
  char* ws = (char*)d_ws;

  int* cw = (int*)ws;
  int* counts = cw;                 // 8
  int* fill   = cw + 8;             // 8
  int* offsets= cw + 16;            // 8
  int* ntiles = cw + 24;            // 1 (+pad)
  int* te = cw + 32;                // 264
  int* tb = cw + 296;               // 264
  int* ts = cw + 560;               // 264
  int* tidx       = cw + 824;                 // PAIRS
  int* token_list = cw + 824 + PAIRS;         // PAIRS
  int* posmap     = cw + 824 + 2*PAIRS;       // PAIRS
  float* tw       = (float*)(cw + 824 + 3*PAIRS); // PAIRS

  const size_t MB = 1u<<20;
  bf16* xb  = (bf16*)(ws + 1*MB);           // 16 MiB
  bf16* w1T = (bf16*)(ws + 17*MB);          // 16 MiB
  bf16* w3T = (bf16*)(ws + 33*MB);          // 16 MiB
  bf16* w2T = (bf16*)(ws + 49*MB);          // 16 MiB
  bf16* Hbuf= (bf16*)(ws + 65*MB);          // PAIRS*FDIM*2 = 128 MiB
  bf16* Obuf= (bf16*)(ws + 17*MB);          // aliases w1T+w3T (32 MiB), dead by gemmB
  size_t needed = 65*MB + (size_t)PAIRS*FDIM*2u;
  if(ws_size < needed) return;

  hipMemsetAsync(d_ws, 0, 64, stream);      // counts + fill

  k_gate<<<N_TOK/8, 512, 0, stream>>>(x, gw, tidx, tw);
  k_count<<<PAIRS/1024, 256, 0, stream>>>(tidx, counts);
  k_route<<<1, 64, 0, stream>>>(counts, offsets, ntiles, te, tb, ts);
  k_scatter<<<PAIRS/256, 256, 0, stream>>>(tidx, offsets, fill, token_list, posmap);
  k_cast<<<(N_TOK*DIM/8)/256, 256, 0, stream>>>(x, xb);
  k_transpose<<<dim3(FDIM/32, DIM/32, NEXP), 256, 0, stream>>>(w1, w1T, DIM, FDIM);
  k_transpose<<<dim3(FDIM/32, DIM/32, NEXP), 256, 0, stream>>>(w3, w3T, DIM, FDIM);
  k_transpose<<<dim3(DIM/32, FDIM/32, NEXP), 256, 0, stream>>>(w2, w2T, FDIM, DIM);
  k_gemmA<<<dim3(MAX_TILES, FDIM/128), 256, 0, stream>>>(xb, w1T, w3T, ntiles, te, tb, ts, token_list, Hbuf);
  k_gemmB<<<dim3(MAX_TILES, DIM/128), 256, 0, stream>>>(Hbuf, w2T, ntiles, te, tb, ts, Obuf);
  k_combine<<<N_TOK/4, 256, 0, stream>>>(Obuf, posmap, tw, out);
}